// Round 3
// baseline (9515.865 us; speedup 1.0000x reference)
//
#include <hip/hip_runtime.h>
#include <math.h>

#define NN 100000
#define NE 400000
#define ET (NN + NE)      // edges + self loops = 500000
#define HID 128
#define HEADS 4
#define NG 2000
#define BN_EPS 1e-5f
#define NEG_SLOPE 0.2f

static __device__ __forceinline__ void atomicMaxF(float* addr, float val) {
    // int-ordering trick: works for mixed signs with -inf init
    if (val >= 0.f) atomicMax((int*)addr, __float_as_int(val));
    else            atomicMin((unsigned int*)addr, __float_as_uint(val));
}

__global__ void k_fill(float* __restrict__ p, float v, long n) {
    long i = (long)blockIdx.x * blockDim.x + threadIdx.x;
    if (i < n) p[i] = v;
}

__global__ void k_deg(const int* __restrict__ dst, float* __restrict__ deg) {
    int e = blockIdx.x * blockDim.x + threadIdx.x;
    if (e < NE) atomicAdd(&deg[dst[e]], 1.f);
}

__global__ void k_dinv(float* __restrict__ deg) {
    int n = blockIdx.x * blockDim.x + threadIdx.x;
    if (n < NN) deg[n] = rsqrtf(deg[n]);   // deg >= 1 (self loop)
}

__global__ void k_enorm(const int* __restrict__ src, const int* __restrict__ dst,
                        const float* __restrict__ dinv, float* __restrict__ enorm) {
    int e = blockIdx.x * blockDim.x + threadIdx.x;
    if (e >= ET) return;
    int s, d;
    if (e < NE) { s = src[e]; d = dst[e]; } else { s = d = e - NE; }
    enorm[e] = dinv[s] * dinv[d];
}

// C[r, c] = sum_k A[r,k] * W[k*ldw + coffW + c], 16 rows/block, K=128, 128 out cols
// LDS: 64x128 W tile (32KB) + 16x128 A tile (8KB) = 40KB
__global__ __launch_bounds__(256) void k_gemm128(const float* __restrict__ A,
                                                 const float* __restrict__ W,
                                                 float* __restrict__ C,
                                                 int nrows, int ldw, int coffW) {
    __shared__ float Ws[64][128];
    __shared__ float As[16][128];
    int tid = threadIdx.x;
    int row0 = blockIdx.x * 16;
    for (int i = tid; i < 16 * 128; i += 256) {
        int r = i >> 7, k = i & 127;
        int gr = row0 + r;
        As[r][k] = (gr < nrows) ? A[(long)gr * 128 + k] : 0.f;
    }
    int c0 = (tid & 31) * 4;   // 4 consecutive cols
    int rp = tid >> 5;         // rows rp and rp+8
    float acc0[4] = {0.f, 0.f, 0.f, 0.f};
    float acc1[4] = {0.f, 0.f, 0.f, 0.f};
    for (int kb = 0; kb < 2; ++kb) {
        __syncthreads();
        for (int i = tid; i < 64 * 128; i += 256) {
            int k = i >> 7, c = i & 127;
            Ws[k][c] = W[(kb * 64 + k) * ldw + coffW + c];
        }
        __syncthreads();
        for (int k = 0; k < 64; ++k) {
            float4 wv = *(const float4*)&Ws[k][c0];
            float a0 = As[rp][kb * 64 + k];
            float a1 = As[rp + 8][kb * 64 + k];
            acc0[0] += a0 * wv.x; acc0[1] += a0 * wv.y; acc0[2] += a0 * wv.z; acc0[3] += a0 * wv.w;
            acc1[0] += a1 * wv.x; acc1[1] += a1 * wv.y; acc1[2] += a1 * wv.z; acc1[3] += a1 * wv.w;
        }
    }
    int gr0 = row0 + rp;
    if (gr0 < nrows) *(float4*)&C[(long)gr0 * 128 + c0] = make_float4(acc0[0], acc0[1], acc0[2], acc0[3]);
    int gr1 = row0 + rp + 8;
    if (gr1 < nrows) *(float4*)&C[(long)gr1 * 128 + c0] = make_float4(acc1[0], acc1[1], acc1[2], acc1[3]);
}

__global__ void k_scatter128(const float* __restrict__ t, const float* __restrict__ enorm,
                             const int* __restrict__ src, const int* __restrict__ dst,
                             float* __restrict__ agg) {
    long idx = (long)blockIdx.x * blockDim.x + threadIdx.x;
    if (idx >= (long)ET * HID) return;
    int e = (int)(idx >> 7);
    int d = (int)(idx & 127);
    int s, dd;
    if (e < NE) { s = src[e]; dd = dst[e]; } else { s = dd = e - NE; }
    atomicAdd(&agg[(long)dd * HID + d], t[(long)s * HID + d] * enorm[e]);
}

__global__ void k_gcn_post(const float* __restrict__ agg, const float* __restrict__ b,
                           const float* __restrict__ gamma, const float* __restrict__ beta,
                           const float* __restrict__ mean, const float* __restrict__ var,
                           float* __restrict__ h, int residual) {
    long idx = (long)blockIdx.x * blockDim.x + threadIdx.x;
    if (idx >= (long)NN * HID) return;
    int d = (int)(idx & 127);
    float v = agg[idx] + b[d];
    v = (v - mean[d]) * rsqrtf(var[d] + BN_EPS) * gamma[d] + beta[d];
    v = fmaxf(v, 0.f);
    h[idx] = residual ? (h[idx] + v) : v;
}

// per-head: a_s[n] = dot(t[n,:], att_s), a_d[n] = dot(t[n,:], att_d)
__global__ __launch_bounds__(128) void k_gat_scores(const float* __restrict__ t,
                                                    const float* __restrict__ att_s,
                                                    const float* __restrict__ att_d,
                                                    float* __restrict__ a_s,
                                                    float* __restrict__ a_d) {
    int n = blockIdx.x;
    int d = threadIdx.x;   // 128 threads = 2 waves
    float v = t[(long)n * 128 + d];
    float ps = v * att_s[d];
    float pd = v * att_d[d];
#pragma unroll
    for (int off = 32; off > 0; off >>= 1) {
        ps += __shfl_down(ps, off, 64);
        pd += __shfl_down(pd, off, 64);
    }
    __shared__ float sm[2][2];
    int wv = d >> 6;
    if ((d & 63) == 0) { sm[wv][0] = ps; sm[wv][1] = pd; }
    __syncthreads();
    if (d == 0) a_s[n] = sm[0][0] + sm[1][0];
    else if (d == 1) a_d[n] = sm[0][1] + sm[1][1];
}

__global__ void k_edge_max(const int* __restrict__ src, const int* __restrict__ dst,
                           const float* __restrict__ a_s, const float* __restrict__ a_d,
                           float* __restrict__ est, float* __restrict__ emax) {
    int e = blockIdx.x * blockDim.x + threadIdx.x;
    if (e >= ET) return;
    int s, dd;
    if (e < NE) { s = src[e]; dd = dst[e]; } else { s = dd = e - NE; }
    float v = a_s[s] + a_d[dd];
    v = (v > 0.f) ? v : NEG_SLOPE * v;
    est[e] = v;
    atomicMaxF(&emax[dd], v);
}

__global__ void k_edge_exp(const int* __restrict__ dst, float* __restrict__ est,
                           const float* __restrict__ emax, float* __restrict__ denom) {
    int e = blockIdx.x * blockDim.x + threadIdx.x;
    if (e >= ET) return;
    int dd = (e < NE) ? dst[e] : e - NE;
    float ex = expf(est[e] - emax[dd]);
    est[e] = ex;
    atomicAdd(&denom[dd], ex);
}

// agg[dd,d] += 0.25 * t[s,d] * est[e] / (denom[dd]+1e-16)
__global__ void k_gat_scatter(const float* __restrict__ t, const float* __restrict__ est,
                              const float* __restrict__ denom,
                              const int* __restrict__ src, const int* __restrict__ dst,
                              float* __restrict__ agg) {
    long idx = (long)blockIdx.x * blockDim.x + threadIdx.x;
    if (idx >= (long)ET * HID) return;
    int e = (int)(idx >> 7);
    int d = (int)(idx & 127);
    int s, dd;
    if (e < NE) { s = src[e]; dd = dst[e]; } else { s = dd = e - NE; }
    float alpha = est[e] / (denom[dd] + 1e-16f);
    atomicAdd(&agg[(long)dd * HID + d], 0.25f * t[(long)s * HID + d] * alpha);
}

__global__ void k_gat_post(const float* __restrict__ am, const float* __restrict__ gat_b,
                           float* __restrict__ h) {
    long idx = (long)blockIdx.x * blockDim.x + threadIdx.x;
    if (idx >= (long)NN * HID) return;
    int d = (int)(idx & 127);
    h[idx] += am[idx] + gat_b[d];
}

__global__ void k_pool(const float* __restrict__ h, const int* __restrict__ batch,
                       float* __restrict__ gsum, float* __restrict__ cnt) {
    long idx = (long)blockIdx.x * blockDim.x + threadIdx.x;
    if (idx >= (long)NN * HID) return;
    int n = (int)(idx >> 7);
    int d = (int)(idx & 127);
    int g = batch[n];
    atomicAdd(&gsum[(long)g * HID + d], h[idx]);
    if (d == 0) atomicAdd(&cnt[g], 1.f);
}

__global__ void k_gdiv(float* __restrict__ gsum, const float* __restrict__ cnt) {
    long idx = (long)blockIdx.x * blockDim.x + threadIdx.x;
    if (idx >= (long)NG * HID) return;
    int g = (int)(idx >> 7);
    gsum[idx] /= fmaxf(cnt[g], 1.f);
}

__global__ __launch_bounds__(64) void k_cls1(const float* __restrict__ g, const float* __restrict__ W,
                                             const float* __restrict__ b, float* __restrict__ z) {
    int gi = blockIdx.x;
    int j = threadIdx.x;   // 64
    float acc = b[j];
    for (int d = 0; d < 128; ++d) acc += g[(long)gi * 128 + d] * W[d * 64 + j];
    z[(long)gi * 64 + j] = fmaxf(acc, 0.f);
}

__global__ __launch_bounds__(64) void k_cls2(const float* __restrict__ z1, const float* __restrict__ W,
                                             const float* __restrict__ b, float* __restrict__ z) {
    int gi = blockIdx.x * 2 + (threadIdx.x >> 5);
    int j = threadIdx.x & 31;   // 32 cols
    if (gi >= NG) return;
    float acc = b[j];
    for (int d = 0; d < 64; ++d) acc += z1[(long)gi * 64 + d] * W[d * 32 + j];
    z[(long)gi * 32 + j] = fmaxf(acc, 0.f);
}

__global__ void k_cls3(const float* __restrict__ z2, const float* __restrict__ W,
                       const float* __restrict__ b, float* __restrict__ out) {
    int gi = blockIdx.x * blockDim.x + threadIdx.x;
    if (gi >= NG) return;
    float acc = b[0];
    for (int d = 0; d < 32; ++d) acc += z2[(long)gi * 32 + d] * W[d];
    out[gi] = acc;
}

extern "C" void kernel_launch(void* const* d_in, const int* in_sizes, int n_in,
                              void* d_out, int out_size, void* d_ws, size_t ws_size,
                              hipStream_t stream) {
    const float* x     = (const float*)d_in[0];
    const int*   ei    = (const int*)d_in[1];
    const int*   src   = ei;            // edge_index[0]
    const int*   dst   = ei + NE;       // edge_index[1]
    const int*   batch = (const int*)d_in[2];
    const float* gcn_W = (const float*)d_in[3];
    const float* gcn_b = (const float*)d_in[4];
    const float* bn_g  = (const float*)d_in[5];
    const float* bn_be = (const float*)d_in[6];
    const float* bn_m  = (const float*)d_in[7];
    const float* bn_v  = (const float*)d_in[8];
    const float* gat_W = (const float*)d_in[9];
    const float* att_s = (const float*)d_in[10];
    const float* att_d = (const float*)d_in[11];
    const float* gat_b = (const float*)d_in[12];
    const float* c1W = (const float*)d_in[13];
    const float* c1b = (const float*)d_in[14];
    const float* c2W = (const float*)d_in[15];
    const float* c2b = (const float*)d_in[16];
    const float* c3W = (const float*)d_in[17];
    const float* c3b = (const float*)d_in[18];
    float* out = (float*)d_out;

    // workspace: ~40M floats = ~160 MB
    float* ws = (float*)d_ws;
    size_t o = 0;
    float* deg   = ws + o; o += NN;                       // then reused as dinv
    float* ebuf  = ws + o; o += ET;                       // enorm (GCN) / est (GAT)
    float* h     = ws + o; o += (size_t)NN * HID;
    float* t     = ws + o; o += (size_t)NN * HID;         // GCN gemm out / GAT per-head hh
    float* agg   = ws + o; o += (size_t)NN * HID;         // scatter accumulator
    float* a_s   = ws + o; o += NN;
    float* a_d   = ws + o; o += NN;
    float* emax  = ws + o; o += NN;
    float* denom = ws + o; o += NN;
    float* gsum  = ws + o; o += (size_t)NG * HID;
    float* cnt   = ws + o; o += NG;                       // contiguous after gsum
    float* z1    = ws + o; o += (size_t)NG * 64;
    float* z2    = ws + o; o += (size_t)NG * 32;

    auto cdiv = [](long a, long b) { return (int)((a + b - 1) / b); };

    // ---- degree normalization ----
    k_fill<<<cdiv(NN, 256), 256, 0, stream>>>(deg, 1.f, NN);
    k_deg<<<cdiv(NE, 256), 256, 0, stream>>>(dst, deg);
    k_dinv<<<cdiv(NN, 256), 256, 0, stream>>>(deg);
    k_enorm<<<cdiv(ET, 256), 256, 0, stream>>>(src, dst, deg, ebuf);

    // ---- 3 GCN layers ----
    const float* hin = x;
    for (int L = 0; L < 3; ++L) {
        k_gemm128<<<cdiv(NN, 16), 256, 0, stream>>>(hin, gcn_W + (size_t)L * HID * HID, t, NN, HID, 0);
        k_fill<<<cdiv((long)NN * HID, 256), 256, 0, stream>>>(agg, 0.f, (long)NN * HID);
        k_scatter128<<<cdiv((long)ET * HID, 256), 256, 0, stream>>>(t, ebuf, src, dst, agg);
        k_gcn_post<<<cdiv((long)NN * HID, 256), 256, 0, stream>>>(
            agg, gcn_b + L * HID, bn_g + L * HID, bn_be + L * HID,
            bn_m + L * HID, bn_v + L * HID, h, L > 0);
        hin = h;
    }

    // ---- GAT: one head at a time (t = hh_head, agg accumulates head mean) ----
    k_fill<<<cdiv((long)NN * HID, 256), 256, 0, stream>>>(agg, 0.f, (long)NN * HID);
    for (int hd = 0; hd < HEADS; ++hd) {
        k_gemm128<<<cdiv(NN, 16), 256, 0, stream>>>(h, gat_W, t, NN, HEADS * HID, hd * HID);
        k_gat_scores<<<NN, 128, 0, stream>>>(t, att_s + hd * HID, att_d + hd * HID, a_s, a_d);
        k_fill<<<cdiv(NN, 256), 256, 0, stream>>>(emax, -INFINITY, NN);
        k_edge_max<<<cdiv(ET, 256), 256, 0, stream>>>(src, dst, a_s, a_d, ebuf, emax);
        k_fill<<<cdiv(NN, 256), 256, 0, stream>>>(denom, 0.f, NN);
        k_edge_exp<<<cdiv(ET, 256), 256, 0, stream>>>(dst, ebuf, emax, denom);
        k_gat_scatter<<<cdiv((long)ET * HID, 256), 256, 0, stream>>>(t, ebuf, denom, src, dst, agg);
    }
    k_gat_post<<<cdiv((long)NN * HID, 256), 256, 0, stream>>>(agg, gat_b, h);

    // ---- global mean pool + classifier ----
    k_fill<<<cdiv((long)(NG * HID + NG), 256), 256, 0, stream>>>(gsum, 0.f, (long)(NG * HID + NG));
    k_pool<<<cdiv((long)NN * HID, 256), 256, 0, stream>>>(h, batch, gsum, cnt);
    k_gdiv<<<cdiv((long)NG * HID, 256), 256, 0, stream>>>(gsum, cnt);
    k_cls1<<<NG, 64, 0, stream>>>(gsum, c1W, c1b, z1);
    k_cls2<<<NG / 2, 64, 0, stream>>>(z1, c2W, c2b, z2);
    k_cls3<<<cdiv(NG, 256), 256, 0, stream>>>(z2, c3W, c3b, out);
}

// Round 5
// 2611.691 us; speedup vs baseline: 3.6436x; 3.6436x over previous
//
#include <hip/hip_runtime.h>
#include <math.h>

#define NN 100000
#define NE 400000
#define ET (NN + NE)      // edges + self loops = 500000
#define HID 128
#define HEADS 4
#define NG 2000
#define BN_EPS 1e-5f
#define NEG_SLOPE 0.2f

static __device__ __forceinline__ void atomicMaxF(float* addr, float val) {
    // int-ordering trick: works for mixed signs with -inf init
    if (val >= 0.f) atomicMax((int*)addr, __float_as_int(val));
    else            atomicMin((unsigned int*)addr, __float_as_uint(val));
}

__global__ void k_fill(float* __restrict__ p, float v, long n) {
    long i = (long)blockIdx.x * blockDim.x + threadIdx.x;
    if (i < n) p[i] = v;
}

__global__ void k_deg(const int* __restrict__ dst, float* __restrict__ deg) {
    int e = blockIdx.x * blockDim.x + threadIdx.x;
    if (e < NE) atomicAdd(&deg[dst[e]], 1.f);
}

__global__ void k_dinv(float* __restrict__ deg) {
    int n = blockIdx.x * blockDim.x + threadIdx.x;
    if (n < NN) deg[n] = rsqrtf(deg[n]);   // deg >= 1 (self loop)
}

__global__ void k_enorm(const int* __restrict__ src, const int* __restrict__ dst,
                        const float* __restrict__ dinv, float* __restrict__ enorm) {
    int e = blockIdx.x * blockDim.x + threadIdx.x;
    if (e >= ET) return;
    int s, d;
    if (e < NE) { s = src[e]; d = dst[e]; } else { s = d = e - NE; }
    enorm[e] = dinv[s] * dinv[d];
}

// C[r, c] = sum_k A[r,k] * W[k*ldw + coffW + c]
// 128x128 tile per 512-thread block; K=128 in two 64-halves.
// LDS: Ws[64][128] (32KB) + As[128][64] (32KB) = 64KB.
// Each thread: 8 rows x 4 cols register tile (32 acc, static indices).
__global__ __launch_bounds__(512) void k_gemm128(const float* __restrict__ A,
                                                 const float* __restrict__ W,
                                                 float* __restrict__ C,
                                                 int nrows, int ldw, int coffW) {
    __shared__ float Ws[64][128];
    __shared__ float As[128][64];
    int tid = threadIdx.x;
    int row0 = blockIdx.x * 128;
    int c0 = (tid & 31) * 4;      // 4 consecutive output cols
    int r0 = (tid >> 5) * 8;      // 8 consecutive output rows
    float acc[8][4] = {};
    for (int kb = 0; kb < 2; ++kb) {
        __syncthreads();
        // stage W half-K: 64 rows x 128 cols = 2048 float4
        for (int i = tid; i < 2048; i += 512) {
            int k  = i >> 5;            // 0..63
            int c4 = (i & 31) * 4;
            *(float4*)&Ws[k][c4] =
                *(const float4*)&W[(long)(kb * 64 + k) * ldw + coffW + c4];
        }
        // stage A half-K: 128 rows x 64 k = 2048 float4
        for (int i = tid; i < 2048; i += 512) {
            int r  = i >> 4;            // 0..127
            int k4 = (i & 15) * 4;
            int gr = row0 + r;
            float4 v = (gr < nrows)
                ? *(const float4*)&A[(long)gr * 128 + kb * 64 + k4]
                : make_float4(0.f, 0.f, 0.f, 0.f);
            *(float4*)&As[r][k4] = v;
        }
        __syncthreads();
        for (int k = 0; k < 64; ++k) {
            float4 wv = *(const float4*)&Ws[k][c0];
#pragma unroll
            for (int j = 0; j < 8; ++j) {
                float a = As[r0 + j][k];
                acc[j][0] += a * wv.x;
                acc[j][1] += a * wv.y;
                acc[j][2] += a * wv.z;
                acc[j][3] += a * wv.w;
            }
        }
    }
#pragma unroll
    for (int j = 0; j < 8; ++j) {
        int gr = row0 + r0 + j;
        if (gr < nrows)
            *(float4*)&C[(long)gr * 128 + c0] =
                make_float4(acc[j][0], acc[j][1], acc[j][2], acc[j][3]);
    }
}

__global__ void k_scatter128(const float* __restrict__ t, const float* __restrict__ enorm,
                             const int* __restrict__ src, const int* __restrict__ dst,
                             float* __restrict__ agg) {
    long idx = (long)blockIdx.x * blockDim.x + threadIdx.x;
    if (idx >= (long)ET * HID) return;
    int e = (int)(idx >> 7);
    int d = (int)(idx & 127);
    int s, dd;
    if (e < NE) { s = src[e]; dd = dst[e]; } else { s = dd = e - NE; }
    atomicAdd(&agg[(long)dd * HID + d], t[(long)s * HID + d] * enorm[e]);
}

__global__ void k_gcn_post(const float* __restrict__ agg, const float* __restrict__ b,
                           const float* __restrict__ gamma, const float* __restrict__ beta,
                           const float* __restrict__ mean, const float* __restrict__ var,
                           float* __restrict__ h, int residual) {
    long idx = (long)blockIdx.x * blockDim.x + threadIdx.x;
    if (idx >= (long)NN * HID) return;
    int d = (int)(idx & 127);
    float v = agg[idx] + b[d];
    v = (v - mean[d]) * rsqrtf(var[d] + BN_EPS) * gamma[d] + beta[d];
    v = fmaxf(v, 0.f);
    h[idx] = residual ? (h[idx] + v) : v;
}

// per-head: a_s[n] = dot(t[n,:], att_s), a_d[n] = dot(t[n,:], att_d)
__global__ __launch_bounds__(128) void k_gat_scores(const float* __restrict__ t,
                                                    const float* __restrict__ att_s,
                                                    const float* __restrict__ att_d,
                                                    float* __restrict__ a_s,
                                                    float* __restrict__ a_d) {
    int n = blockIdx.x;
    int d = threadIdx.x;   // 128 threads = 2 waves
    float v = t[(long)n * 128 + d];
    float ps = v * att_s[d];
    float pd = v * att_d[d];
#pragma unroll
    for (int off = 32; off > 0; off >>= 1) {
        ps += __shfl_down(ps, off, 64);
        pd += __shfl_down(pd, off, 64);
    }
    __shared__ float sm[2][2];
    int wv = d >> 6;
    if ((d & 63) == 0) { sm[wv][0] = ps; sm[wv][1] = pd; }
    __syncthreads();
    if (d == 0) a_s[n] = sm[0][0] + sm[1][0];
    else if (d == 1) a_d[n] = sm[0][1] + sm[1][1];
}

__global__ void k_edge_max(const int* __restrict__ src, const int* __restrict__ dst,
                           const float* __restrict__ a_s, const float* __restrict__ a_d,
                           float* __restrict__ est, float* __restrict__ emax) {
    int e = blockIdx.x * blockDim.x + threadIdx.x;
    if (e >= ET) return;
    int s, dd;
    if (e < NE) { s = src[e]; dd = dst[e]; } else { s = dd = e - NE; }
    float v = a_s[s] + a_d[dd];
    v = (v > 0.f) ? v : NEG_SLOPE * v;
    est[e] = v;
    atomicMaxF(&emax[dd], v);
}

__global__ void k_edge_exp(const int* __restrict__ dst, float* __restrict__ est,
                           const float* __restrict__ emax, float* __restrict__ denom) {
    int e = blockIdx.x * blockDim.x + threadIdx.x;
    if (e >= ET) return;
    int dd = (e < NE) ? dst[e] : e - NE;
    float ex = expf(est[e] - emax[dd]);
    est[e] = ex;
    atomicAdd(&denom[dd], ex);
}

// agg[dd,d] += 0.25 * t[s,d] * est[e] / (denom[dd]+1e-16)
__global__ void k_gat_scatter(const float* __restrict__ t, const float* __restrict__ est,
                              const float* __restrict__ denom,
                              const int* __restrict__ src, const int* __restrict__ dst,
                              float* __restrict__ agg) {
    long idx = (long)blockIdx.x * blockDim.x + threadIdx.x;
    if (idx >= (long)ET * HID) return;
    int e = (int)(idx >> 7);
    int d = (int)(idx & 127);
    int s, dd;
    if (e < NE) { s = src[e]; dd = dst[e]; } else { s = dd = e - NE; }
    float alpha = est[e] / (denom[dd] + 1e-16f);
    atomicAdd(&agg[(long)dd * HID + d], 0.25f * t[(long)s * HID + d] * alpha);
}

__global__ void k_gat_post(const float* __restrict__ am, const float* __restrict__ gat_b,
                           float* __restrict__ h) {
    long idx = (long)blockIdx.x * blockDim.x + threadIdx.x;
    if (idx >= (long)NN * HID) return;
    int d = (int)(idx & 127);
    h[idx] += am[idx] + gat_b[d];
}

__global__ void k_pool(const float* __restrict__ h, const int* __restrict__ batch,
                       float* __restrict__ gsum, float* __restrict__ cnt) {
    long idx = (long)blockIdx.x * blockDim.x + threadIdx.x;
    if (idx >= (long)NN * HID) return;
    int n = (int)(idx >> 7);
    int d = (int)(idx & 127);
    int g = batch[n];
    atomicAdd(&gsum[(long)g * HID + d], h[idx]);
    if (d == 0) atomicAdd(&cnt[g], 1.f);
}

__global__ void k_gdiv(float* __restrict__ gsum, const float* __restrict__ cnt) {
    long idx = (long)blockIdx.x * blockDim.x + threadIdx.x;
    if (idx >= (long)NG * HID) return;
    int g = (int)(idx >> 7);
    gsum[idx] /= fmaxf(cnt[g], 1.f);
}

__global__ __launch_bounds__(64) void k_cls1(const float* __restrict__ g, const float* __restrict__ W,
                                             const float* __restrict__ b, float* __restrict__ z) {
    int gi = blockIdx.x;
    int j = threadIdx.x;   // 64
    float acc = b[j];
    for (int d = 0; d < 128; ++d) acc += g[(long)gi * 128 + d] * W[d * 64 + j];
    z[(long)gi * 64 + j] = fmaxf(acc, 0.f);
}

__global__ __launch_bounds__(64) void k_cls2(const float* __restrict__ z1, const float* __restrict__ W,
                                             const float* __restrict__ b, float* __restrict__ z) {
    int gi = blockIdx.x * 2 + (threadIdx.x >> 5);
    int j = threadIdx.x & 31;   // 32 cols
    if (gi >= NG) return;
    float acc = b[j];
    for (int d = 0; d < 64; ++d) acc += z1[(long)gi * 64 + d] * W[d * 32 + j];
    z[(long)gi * 32 + j] = fmaxf(acc, 0.f);
}

__global__ void k_cls3(const float* __restrict__ z2, const float* __restrict__ W,
                       const float* __restrict__ b, float* __restrict__ out) {
    int gi = blockIdx.x * blockDim.x + threadIdx.x;
    if (gi >= NG) return;
    float acc = b[0];
    for (int d = 0; d < 32; ++d) acc += z2[(long)gi * 32 + d] * W[d];
    out[gi] = acc;
}

extern "C" void kernel_launch(void* const* d_in, const int* in_sizes, int n_in,
                              void* d_out, int out_size, void* d_ws, size_t ws_size,
                              hipStream_t stream) {
    const float* x     = (const float*)d_in[0];
    const int*   ei    = (const int*)d_in[1];
    const int*   src   = ei;            // edge_index[0]
    const int*   dst   = ei + NE;       // edge_index[1]
    const int*   batch = (const int*)d_in[2];
    const float* gcn_W = (const float*)d_in[3];
    const float* gcn_b = (const float*)d_in[4];
    const float* bn_g  = (const float*)d_in[5];
    const float* bn_be = (const float*)d_in[6];
    const float* bn_m  = (const float*)d_in[7];
    const float* bn_v  = (const float*)d_in[8];
    const float* gat_W = (const float*)d_in[9];
    const float* att_s = (const float*)d_in[10];
    const float* att_d = (const float*)d_in[11];
    const float* gat_b = (const float*)d_in[12];
    const float* c1W = (const float*)d_in[13];
    const float* c1b = (const float*)d_in[14];
    const float* c2W = (const float*)d_in[15];
    const float* c2b = (const float*)d_in[16];
    const float* c3W = (const float*)d_in[17];
    const float* c3b = (const float*)d_in[18];
    float* out = (float*)d_out;

    // workspace: ~40M floats = ~160 MB
    float* ws = (float*)d_ws;
    size_t o = 0;
    float* deg   = ws + o; o += NN;                       // then reused as dinv
    float* ebuf  = ws + o; o += ET;                       // enorm (GCN) / est (GAT)
    float* h     = ws + o; o += (size_t)NN * HID;
    float* t     = ws + o; o += (size_t)NN * HID;         // GCN gemm out / GAT per-head hh
    float* agg   = ws + o; o += (size_t)NN * HID;         // scatter accumulator
    float* a_s   = ws + o; o += NN;
    float* a_d   = ws + o; o += NN;
    float* emax  = ws + o; o += NN;
    float* denom = ws + o; o += NN;
    float* gsum  = ws + o; o += (size_t)NG * HID;
    float* cnt   = ws + o; o += NG;                       // contiguous after gsum
    float* z1    = ws + o; o += (size_t)NG * 64;
    float* z2    = ws + o; o += (size_t)NG * 32;

    auto cdiv = [](long a, long b) { return (int)((a + b - 1) / b); };

    // ---- degree normalization ----
    k_fill<<<cdiv(NN, 256), 256, 0, stream>>>(deg, 1.f, NN);
    k_deg<<<cdiv(NE, 256), 256, 0, stream>>>(dst, deg);
    k_dinv<<<cdiv(NN, 256), 256, 0, stream>>>(deg);
    k_enorm<<<cdiv(ET, 256), 256, 0, stream>>>(src, dst, deg, ebuf);

    // ---- 3 GCN layers ----
    const float* hin = x;
    for (int L = 0; L < 3; ++L) {
        k_gemm128<<<cdiv(NN, 128), 512, 0, stream>>>(hin, gcn_W + (size_t)L * HID * HID, t, NN, HID, 0);
        k_fill<<<cdiv((long)NN * HID, 256), 256, 0, stream>>>(agg, 0.f, (long)NN * HID);
        k_scatter128<<<cdiv((long)ET * HID, 256), 256, 0, stream>>>(t, ebuf, src, dst, agg);
        k_gcn_post<<<cdiv((long)NN * HID, 256), 256, 0, stream>>>(
            agg, gcn_b + L * HID, bn_g + L * HID, bn_be + L * HID,
            bn_m + L * HID, bn_v + L * HID, h, L > 0);
        hin = h;
    }

    // ---- GAT: one head at a time (t = hh_head, agg accumulates head mean) ----
    k_fill<<<cdiv((long)NN * HID, 256), 256, 0, stream>>>(agg, 0.f, (long)NN * HID);
    for (int hd = 0; hd < HEADS; ++hd) {
        k_gemm128<<<cdiv(NN, 128), 512, 0, stream>>>(h, gat_W, t, NN, HEADS * HID, hd * HID);
        k_gat_scores<<<NN, 128, 0, stream>>>(t, att_s + hd * HID, att_d + hd * HID, a_s, a_d);
        k_fill<<<cdiv(NN, 256), 256, 0, stream>>>(emax, -INFINITY, NN);
        k_edge_max<<<cdiv(ET, 256), 256, 0, stream>>>(src, dst, a_s, a_d, ebuf, emax);
        k_fill<<<cdiv(NN, 256), 256, 0, stream>>>(denom, 0.f, NN);
        k_edge_exp<<<cdiv(ET, 256), 256, 0, stream>>>(dst, ebuf, emax, denom);
        k_gat_scatter<<<cdiv((long)ET * HID, 256), 256, 0, stream>>>(t, ebuf, denom, src, dst, agg);
    }
    k_gat_post<<<cdiv((long)NN * HID, 256), 256, 0, stream>>>(agg, gat_b, h);

    // ---- global mean pool + classifier ----
    k_fill<<<cdiv((long)(NG * HID + NG), 256), 256, 0, stream>>>(gsum, 0.f, (long)(NG * HID + NG));
    k_pool<<<cdiv((long)NN * HID, 256), 256, 0, stream>>>(h, batch, gsum, cnt);
    k_gdiv<<<cdiv((long)NG * HID, 256), 256, 0, stream>>>(gsum, cnt);
    k_cls1<<<NG, 64, 0, stream>>>(gsum, c1W, c1b, z1);
    k_cls2<<<NG / 2, 64, 0, stream>>>(z1, c2W, c2b, z2);
    k_cls3<<<cdiv(NG, 256), 256, 0, stream>>>(z2, c3W, c3b, out);
}

// Round 6
// 1338.526 us; speedup vs baseline: 7.1092x; 1.9512x over previous
//
#include <hip/hip_runtime.h>
#include <math.h>

#define NN 100000
#define NE 400000
#define HID 128
#define HEADS 4
#define NG 2000
#define BN_EPS 1e-5f
#define NEG_SLOPE 0.2f
#define NB_SCAN 391   // cdiv(NN,256)

__global__ void k_fill(float* __restrict__ p, float v, long n) {
    long i = (long)blockIdx.x * blockDim.x + threadIdx.x;
    if (i < n) p[i] = v;
}

__global__ void k_zero_i(int* __restrict__ p, int n) {
    int i = blockIdx.x * blockDim.x + threadIdx.x;
    if (i < n) p[i] = 0;
}

__global__ void k_count(const int* __restrict__ dst, int* __restrict__ cnt) {
    int e = blockIdx.x * blockDim.x + threadIdx.x;
    if (e < NE) atomicAdd(&cnt[dst[e]], 1);
}

__global__ void k_dinv2(const int* __restrict__ cnt, float* __restrict__ dinv) {
    int n = blockIdx.x * blockDim.x + threadIdx.x;
    if (n < NN) dinv[n] = rsqrtf((float)cnt[n] + 1.0f);   // +1 self loop
}

__global__ __launch_bounds__(256) void k_bsum(const int* __restrict__ cnt, int* __restrict__ bsum) {
    __shared__ int s[256];
    int tid = threadIdx.x;
    int n = blockIdx.x * 256 + tid;
    s[tid] = (n < NN) ? cnt[n] : 0;
    __syncthreads();
    for (int off = 128; off > 0; off >>= 1) {
        if (tid < off) s[tid] += s[tid + off];
        __syncthreads();
    }
    if (tid == 0) bsum[blockIdx.x] = s[0];
}

// exclusive scan of bsum[NB_SCAN] in one block; also set row_ptr[NN]=NE
__global__ __launch_bounds__(512) void k_bscan(int* __restrict__ bsum, int* __restrict__ row_ptr) {
    __shared__ int s[512];
    int tid = threadIdx.x;
    int v = (tid < NB_SCAN) ? bsum[tid] : 0;
    s[tid] = v;
    __syncthreads();
    for (int off = 1; off < 512; off <<= 1) {
        int t_ = (tid >= off) ? s[tid - off] : 0;
        __syncthreads();
        s[tid] += t_;
        __syncthreads();
    }
    if (tid < NB_SCAN) bsum[tid] = s[tid] - v;   // exclusive block offsets
    if (tid == 0) row_ptr[NN] = NE;
}

__global__ __launch_bounds__(256) void k_rowptr(const int* __restrict__ cnt, const int* __restrict__ boff,
                                                int* __restrict__ row_ptr) {
    __shared__ int s[256];
    int tid = threadIdx.x;
    int n = blockIdx.x * 256 + tid;
    int v = (n < NN) ? cnt[n] : 0;
    s[tid] = v;
    __syncthreads();
    for (int off = 1; off < 256; off <<= 1) {
        int t_ = (tid >= off) ? s[tid - off] : 0;
        __syncthreads();
        s[tid] += t_;
        __syncthreads();
    }
    if (n < NN) row_ptr[n] = boff[blockIdx.x] + s[tid] - v;
}

__global__ void k_csr(const int* __restrict__ src, const int* __restrict__ dst,
                      const int* __restrict__ row_ptr, int* __restrict__ fill,
                      const float* __restrict__ dinv,
                      int* __restrict__ csr_src, float* __restrict__ csr_w) {
    int e = blockIdx.x * blockDim.x + threadIdx.x;
    if (e >= NE) return;
    int s = src[e], d = dst[e];
    int pos = row_ptr[d] + atomicAdd(&fill[d], 1);
    csr_src[pos] = s;
    csr_w[pos] = dinv[s] * dinv[d];
}

// C[r, c] = sum_k A[r,k] * W[k*ldw + coffW + c]; optional fused att-score epilogue.
// 128x128 tile per 512-thread block; K=128 in two 64-halves. LDS 64KB.
__global__ __launch_bounds__(512) void k_gemm128(const float* __restrict__ A,
                                                 const float* __restrict__ W,
                                                 float* __restrict__ C,
                                                 int nrows, int ldw, int coffW,
                                                 const float* __restrict__ att_s,
                                                 const float* __restrict__ att_d,
                                                 float* __restrict__ as_out,
                                                 float* __restrict__ ad_out) {
    __shared__ float Ws[64][128];
    __shared__ float As[128][64];
    int tid = threadIdx.x;
    int row0 = blockIdx.x * 128;
    int c0 = (tid & 31) * 4;      // 4 consecutive output cols
    int r0 = (tid >> 5) * 8;      // 8 consecutive output rows
    float acc[8][4] = {};
    for (int kb = 0; kb < 2; ++kb) {
        __syncthreads();
        for (int i = tid; i < 2048; i += 512) {
            int k  = i >> 5;
            int c4 = (i & 31) * 4;
            *(float4*)&Ws[k][c4] =
                *(const float4*)&W[(long)(kb * 64 + k) * ldw + coffW + c4];
        }
        for (int i = tid; i < 2048; i += 512) {
            int r  = i >> 4;
            int k4 = (i & 15) * 4;
            int gr = row0 + r;
            float4 v = (gr < nrows)
                ? *(const float4*)&A[(long)gr * 128 + kb * 64 + k4]
                : make_float4(0.f, 0.f, 0.f, 0.f);
            *(float4*)&As[r][k4] = v;
        }
        __syncthreads();
        for (int k = 0; k < 64; ++k) {
            float4 wv = *(const float4*)&Ws[k][c0];
#pragma unroll
            for (int j = 0; j < 8; ++j) {
                float a = As[r0 + j][k];
                acc[j][0] += a * wv.x;
                acc[j][1] += a * wv.y;
                acc[j][2] += a * wv.z;
                acc[j][3] += a * wv.w;
            }
        }
    }
#pragma unroll
    for (int j = 0; j < 8; ++j) {
        int gr = row0 + r0 + j;
        if (gr < nrows)
            *(float4*)&C[(long)gr * 128 + c0] =
                make_float4(acc[j][0], acc[j][1], acc[j][2], acc[j][3]);
    }
    if (att_s) {
        // per-row dot with att vectors; row r held by 32 consecutive lanes
#pragma unroll
        for (int j = 0; j < 8; ++j) {
            float ps = acc[j][0] * att_s[c0] + acc[j][1] * att_s[c0 + 1]
                     + acc[j][2] * att_s[c0 + 2] + acc[j][3] * att_s[c0 + 3];
            float pd = acc[j][0] * att_d[c0] + acc[j][1] * att_d[c0 + 1]
                     + acc[j][2] * att_d[c0 + 2] + acc[j][3] * att_d[c0 + 3];
#pragma unroll
            for (int off = 16; off > 0; off >>= 1) {
                ps += __shfl_down(ps, off, 32);
                pd += __shfl_down(pd, off, 32);
            }
            int gr = row0 + r0 + j;
            if ((tid & 31) == 0 && gr < nrows) { as_out[gr] = ps; ad_out[gr] = pd; }
        }
    }
}

// fused CSR gather + bias + BN + ReLU + residual (no atomics)
__global__ __launch_bounds__(128) void k_gcn_agg(const float* __restrict__ t,
                                                 const int* __restrict__ row_ptr,
                                                 const int* __restrict__ csr_src,
                                                 const float* __restrict__ csr_w,
                                                 const float* __restrict__ dinv,
                                                 const float* __restrict__ b,
                                                 const float* __restrict__ gamma,
                                                 const float* __restrict__ beta,
                                                 const float* __restrict__ mean,
                                                 const float* __restrict__ var,
                                                 float* __restrict__ h, int residual) {
    int n = blockIdx.x;
    int d = threadIdx.x;
    int e0 = row_ptr[n], e1 = row_ptr[n + 1];
    float dn = dinv[n];
    float acc = t[(long)n * HID + d] * dn * dn;   // self loop
    for (int j = e0; j < e1; ++j)
        acc += t[(long)csr_src[j] * HID + d] * csr_w[j];
    float v = acc + b[d];
    v = (v - mean[d]) * rsqrtf(var[d] + BN_EPS) * gamma[d] + beta[d];
    v = fmaxf(v, 0.f);
    long idx = (long)n * HID + d;
    h[idx] = residual ? (h[idx] + v) : v;
}

// fused per-head GAT: max, single-pass denom + weighted gather, head-mean accumulate
// mode 0: agg = 0.25*att ; mode 1: agg += ; mode 2: h += agg + 0.25*att + gat_b
__global__ __launch_bounds__(128) void k_gat_agg(const float* __restrict__ t,
                                                 const int* __restrict__ row_ptr,
                                                 const int* __restrict__ csr_src,
                                                 const float* __restrict__ a_s,
                                                 const float* __restrict__ a_d,
                                                 const float* __restrict__ gat_b,
                                                 float* __restrict__ agg,
                                                 float* __restrict__ h, int mode) {
    int n = blockIdx.x;
    int d = threadIdx.x;
    int e0 = row_ptr[n], e1 = row_ptr[n + 1];
    float adn = a_d[n];
    float es = a_s[n] + adn;
    es = (es > 0.f) ? es : NEG_SLOPE * es;
    float m = es;
    for (int j = e0; j < e1; ++j) {
        float e = a_s[csr_src[j]] + adn;
        e = (e > 0.f) ? e : NEG_SLOPE * e;
        m = fmaxf(m, e);
    }
    float w0 = expf(es - m);
    float denom = w0;
    float acc = t[(long)n * HID + d] * w0;        // self loop
    for (int j = e0; j < e1; ++j) {
        int s = csr_src[j];
        float e = a_s[s] + adn;
        e = (e > 0.f) ? e : NEG_SLOPE * e;
        float w = expf(e - m);
        denom += w;
        acc += t[(long)s * HID + d] * w;
    }
    acc = 0.25f * acc / (denom + 1e-16f);
    long idx = (long)n * HID + d;
    if (mode == 0)      agg[idx] = acc;
    else if (mode == 1) agg[idx] += acc;
    else                h[idx] += agg[idx] + acc + gat_b[d];
}

__global__ void k_pool(const float* __restrict__ h, const int* __restrict__ batch,
                       float* __restrict__ gsum, float* __restrict__ cnt) {
    long idx = (long)blockIdx.x * blockDim.x + threadIdx.x;
    if (idx >= (long)NN * HID) return;
    int n = (int)(idx >> 7);
    int d = (int)(idx & 127);
    int g = batch[n];
    atomicAdd(&gsum[(long)g * HID + d], h[idx]);
    if (d == 0) atomicAdd(&cnt[g], 1.f);
}

__global__ void k_gdiv(float* __restrict__ gsum, const float* __restrict__ cnt) {
    long idx = (long)blockIdx.x * blockDim.x + threadIdx.x;
    if (idx >= (long)NG * HID) return;
    int g = (int)(idx >> 7);
    gsum[idx] /= fmaxf(cnt[g], 1.f);
}

__global__ __launch_bounds__(64) void k_cls1(const float* __restrict__ g, const float* __restrict__ W,
                                             const float* __restrict__ b, float* __restrict__ z) {
    int gi = blockIdx.x;
    int j = threadIdx.x;   // 64
    float acc = b[j];
    for (int d = 0; d < 128; ++d) acc += g[(long)gi * 128 + d] * W[d * 64 + j];
    z[(long)gi * 64 + j] = fmaxf(acc, 0.f);
}

__global__ __launch_bounds__(64) void k_cls2(const float* __restrict__ z1, const float* __restrict__ W,
                                             const float* __restrict__ b, float* __restrict__ z) {
    int gi = blockIdx.x * 2 + (threadIdx.x >> 5);
    int j = threadIdx.x & 31;   // 32 cols
    if (gi >= NG) return;
    float acc = b[j];
    for (int d = 0; d < 64; ++d) acc += z1[(long)gi * 64 + d] * W[d * 32 + j];
    z[(long)gi * 32 + j] = fmaxf(acc, 0.f);
}

__global__ void k_cls3(const float* __restrict__ z2, const float* __restrict__ W,
                       const float* __restrict__ b, float* __restrict__ out) {
    int gi = blockIdx.x * blockDim.x + threadIdx.x;
    if (gi >= NG) return;
    float acc = b[0];
    for (int d = 0; d < 32; ++d) acc += z2[(long)gi * 32 + d] * W[d];
    out[gi] = acc;
}

extern "C" void kernel_launch(void* const* d_in, const int* in_sizes, int n_in,
                              void* d_out, int out_size, void* d_ws, size_t ws_size,
                              hipStream_t stream) {
    const float* x     = (const float*)d_in[0];
    const int*   ei    = (const int*)d_in[1];
    const int*   src   = ei;            // edge_index[0]
    const int*   dst   = ei + NE;       // edge_index[1]
    const int*   batch = (const int*)d_in[2];
    const float* gcn_W = (const float*)d_in[3];
    const float* gcn_b = (const float*)d_in[4];
    const float* bn_g  = (const float*)d_in[5];
    const float* bn_be = (const float*)d_in[6];
    const float* bn_m  = (const float*)d_in[7];
    const float* bn_v  = (const float*)d_in[8];
    const float* gat_W = (const float*)d_in[9];
    const float* att_s = (const float*)d_in[10];
    const float* att_d = (const float*)d_in[11];
    const float* gat_b = (const float*)d_in[12];
    const float* c1W = (const float*)d_in[13];
    const float* c1b = (const float*)d_in[14];
    const float* c2W = (const float*)d_in[15];
    const float* c2b = (const float*)d_in[16];
    const float* c3W = (const float*)d_in[17];
    const float* c3b = (const float*)d_in[18];
    float* out = (float*)d_out;

    float* ws = (float*)d_ws;
    size_t o = 0;
    float* dinv    = ws + o; o += NN;
    int*   cnt     = (int*)(ws + o); o += NN;              // count, then reused as fill
    int*   bsum    = (int*)(ws + o); o += 512;
    int*   row_ptr = (int*)(ws + o); o += NN + 1;
    int*   csr_src = (int*)(ws + o); o += NE;
    float* csr_w   = ws + o; o += NE;
    float* h       = ws + o; o += (size_t)NN * HID;
    float* t       = ws + o; o += (size_t)NN * HID;
    float* agg     = ws + o; o += (size_t)NN * HID;
    float* a_s     = ws + o; o += NN;
    float* a_d     = ws + o; o += NN;
    float* gsum    = ws + o; o += (size_t)NG * HID;
    float* cntg    = ws + o; o += NG;                      // contiguous after gsum
    float* z1      = ws + o; o += (size_t)NG * 64;
    float* z2      = ws + o; o += (size_t)NG * 32;

    auto cdiv = [](long a, long b) { return (int)((a + b - 1) / b); };

    // ---- CSR build (by dst) + symmetric degree norm ----
    k_zero_i<<<cdiv(NN, 256), 256, 0, stream>>>(cnt, NN);
    k_count<<<cdiv(NE, 256), 256, 0, stream>>>(dst, cnt);
    k_dinv2<<<cdiv(NN, 256), 256, 0, stream>>>(cnt, dinv);
    k_bsum<<<NB_SCAN, 256, 0, stream>>>(cnt, bsum);
    k_bscan<<<1, 512, 0, stream>>>(bsum, row_ptr);
    k_rowptr<<<NB_SCAN, 256, 0, stream>>>(cnt, bsum, row_ptr);
    k_zero_i<<<cdiv(NN, 256), 256, 0, stream>>>(cnt, NN);  // reuse as fill
    k_csr<<<cdiv(NE, 256), 256, 0, stream>>>(src, dst, row_ptr, cnt, dinv, csr_src, csr_w);

    // ---- 3 GCN layers ----
    const float* hin = x;
    for (int L = 0; L < 3; ++L) {
        k_gemm128<<<cdiv(NN, 128), 512, 0, stream>>>(hin, gcn_W + (size_t)L * HID * HID, t,
                                                     NN, HID, 0, nullptr, nullptr, nullptr, nullptr);
        k_gcn_agg<<<NN, 128, 0, stream>>>(t, row_ptr, csr_src, csr_w, dinv,
                                          gcn_b + L * HID, bn_g + L * HID, bn_be + L * HID,
                                          bn_m + L * HID, bn_v + L * HID, h, L > 0);
        hin = h;
    }

    // ---- GAT: per head, fused scores (GEMM epilogue) + fused softmax-gather ----
    for (int hd = 0; hd < HEADS; ++hd) {
        k_gemm128<<<cdiv(NN, 128), 512, 0, stream>>>(h, gat_W, t, NN, HEADS * HID, hd * HID,
                                                     att_s + hd * HID, att_d + hd * HID, a_s, a_d);
        k_gat_agg<<<NN, 128, 0, stream>>>(t, row_ptr, csr_src, a_s, a_d, gat_b, agg, h,
                                          hd == 0 ? 0 : (hd == HEADS - 1 ? 2 : 1));
    }

    // ---- global mean pool + classifier ----
    k_fill<<<cdiv((long)(NG * HID + NG), 256), 256, 0, stream>>>(gsum, 0.f, (long)(NG * HID + NG));
    k_pool<<<cdiv((long)NN * HID, 256), 256, 0, stream>>>(h, batch, gsum, cntg);
    k_gdiv<<<cdiv((long)NG * HID, 256), 256, 0, stream>>>(gsum, cntg);
    k_cls1<<<NG, 64, 0, stream>>>(gsum, c1W, c1b, z1);
    k_cls2<<<NG / 2, 64, 0, stream>>>(z1, c2W, c2b, z2);
    k_cls3<<<cdiv(NG, 256), 256, 0, stream>>>(z2, c3W, c3b, out);
}